// Round 3
// baseline (4970.561 us; speedup 1.0000x reference)
//
#include <hip/hip_runtime.h>
#include <hip/hip_bf16.h>
#include <hip/hip_fp16.h>

typedef _Float16 f16;
typedef _Float16 f16x8 __attribute__((ext_vector_type(8)));
typedef float f32x4 __attribute__((ext_vector_type(4)));
typedef unsigned int u32;
typedef unsigned long long u64;

#define HB 2048
#define DD 2048
#define TT 256
#define BB 64
#define NWG 128

typedef const __attribute__((address_space(1))) u32 gu32;
typedef __attribute__((address_space(3))) u32 lu32;

__device__ __forceinline__ void gl_lds16(const void* g, void* l) {
    __builtin_amdgcn_global_load_lds((gu32*)g, (lu32*)l, 16, 0, 0);
}

// ---------- transpose + convert fp32 [R][C] -> fp16 [C][R] (square 2048) ----------
__global__ __launch_bounds__(256) void k_transpose_cvt(const float* __restrict__ src,
                                                       f16* __restrict__ dst) {
    __shared__ f16 tile[64][65];
    int bx = blockIdx.x * 64;
    int by = blockIdx.y * 64;
    int tx = threadIdx.x & 63;
    int ty = threadIdx.x >> 6;
#pragma unroll
    for (int r = ty; r < 64; r += 4)
        tile[r][tx] = (f16)src[(size_t)(by + r) * HB + bx + tx];
    __syncthreads();
#pragma unroll
    for (int r = ty; r < 64; r += 4)
        dst[(size_t)(bx + r) * HB + by + tx] = tile[tx][r];
}

// ---------- convert/gather x [b][t][d] fp32 -> a16 [t*64+b][d] fp16 ----------
__global__ __launch_bounds__(256) void k_cvt_x(const float* __restrict__ x,
                                               f16* __restrict__ a16) {
    int r = blockIdx.x;  // r = t*64+b
    int d = threadIdx.x * 8;
    const float* src = x + ((size_t)(r & 63) * TT + (r >> 6)) * DD + d;
    float4 v0 = *(const float4*)src;
    float4 v1 = *(const float4*)(src + 4);
    f16x8 o = {(f16)v0.x, (f16)v0.y, (f16)v0.z, (f16)v0.w,
               (f16)v1.x, (f16)v1.y, (f16)v1.z, (f16)v1.w};
    *(f16x8*)(a16 + (size_t)r * DD + d) = o;
}

// ---------- phase 1 (fast): 128x128x32 LDS-staged MFMA GEMM, xw16 = a16 @ W + b ----------
__global__ __launch_bounds__(256) void k_gemm_xw_lds(const f16* __restrict__ a16,
                                                     const f16* __restrict__ W16T,
                                                     const float* __restrict__ bias,
                                                     f16* __restrict__ xw16) {
    __shared__ f16 As[128 * 32];
    __shared__ f16 Bs[128 * 32];
    int tid = threadIdx.x;
    int lane = tid & 63, w = tid >> 6;
    int wr = w >> 1, wc = w & 1;
    int lr = lane & 15, kg = lane >> 4;
    int rowBase = blockIdx.y * 128;
    int colBase = blockIdx.x * 128;

    f32x4 acc[4][4] = {};

    int r0 = tid >> 2, c0 = ((tid & 3) ^ ((r0 >> 1) & 3)) * 8;
    int u1 = tid + 256;
    int r1 = u1 >> 2, c1 = ((u1 & 3) ^ ((r1 >> 1) & 3)) * 8;
    const f16* gA0 = a16 + (size_t)(rowBase + r0) * DD + c0;
    const f16* gA1 = a16 + (size_t)(rowBase + r1) * DD + c1;
    const f16* gB0 = W16T + (size_t)(colBase + r0) * DD + c0;
    const f16* gB1 = W16T + (size_t)(colBase + r1) * DD + c1;
    f16* lA0 = As + (size_t)(w * 64) * 8;
    f16* lA1 = As + (size_t)(256 + w * 64) * 8;
    f16* lB0 = Bs + (size_t)(w * 64) * 8;
    f16* lB1 = Bs + (size_t)(256 + w * 64) * 8;

    for (int kk = 0; kk < DD; kk += 32) {
        gl_lds16(gA0 + kk, lA0);
        gl_lds16(gA1 + kk, lA1);
        gl_lds16(gB0 + kk, lB0);
        gl_lds16(gB1 + kk, lB1);
        __syncthreads();

        f16x8 af[4], bf[4];
#pragma unroll
        for (int mi = 0; mi < 4; ++mi) {
            int row = wr * 64 + mi * 16 + lr;
            af[mi] = *(const f16x8*)(As + row * 32 + (kg ^ ((row >> 1) & 3)) * 8);
        }
#pragma unroll
        for (int ni = 0; ni < 4; ++ni) {
            int rowb = wc * 64 + ni * 16 + lr;
            bf[ni] = *(const f16x8*)(Bs + rowb * 32 + (kg ^ ((rowb >> 1) & 3)) * 8);
        }
#pragma unroll
        for (int mi = 0; mi < 4; ++mi)
#pragma unroll
            for (int ni = 0; ni < 4; ++ni)
                acc[mi][ni] = __builtin_amdgcn_mfma_f32_16x16x32_f16(af[mi], bf[ni],
                                                                     acc[mi][ni], 0, 0, 0);
        __syncthreads();
    }

#pragma unroll
    for (int mi = 0; mi < 4; ++mi)
#pragma unroll
        for (int ni = 0; ni < 4; ++ni) {
            int col = colBase + wc * 64 + ni * 16 + lr;
            float bv = bias[col];
#pragma unroll
            for (int j = 0; j < 4; ++j) {
                int row = rowBase + wr * 64 + mi * 16 + kg * 4 + j;
                xw16[(size_t)row * HB + col] = (f16)(acc[mi][ni][j] + bv);
            }
        }
}

// ---------- phase 1 (fallback, small ws): direct-load GEMM from fp32 x ----------
__global__ __launch_bounds__(256) void k_gemm_xw_direct(const float* __restrict__ x,
                                                        const f16* __restrict__ W16T,
                                                        const float* __restrict__ bias,
                                                        f16* __restrict__ xw16) {
    int lane = threadIdx.x & 63;
    int w = threadIdx.x >> 6;
    int wr = w >> 1, wc = w & 1;
    int rowBase = blockIdx.y * 64 + wr * 32;
    int colBase = blockIdx.x * 64 + wc * 32;
    int lr = lane & 15;
    int kg = lane >> 4;

    f32x4 acc[2][2] = {};

    int r0 = rowBase + lr;
    int r1 = rowBase + 16 + lr;
    const float* xrow0 = x + ((size_t)(r0 & 63) * TT + (r0 >> 6)) * DD;
    const float* xrow1 = x + ((size_t)(r1 & 63) * TT + (r1 >> 6)) * DD;
    const f16* wrow0 = W16T + (size_t)(colBase + lr) * DD;
    const f16* wrow1 = W16T + (size_t)(colBase + 16 + lr) * DD;

    for (int kk = 0; kk < DD; kk += 32) {
        int k = kk + kg * 8;
        const float4* pa0 = reinterpret_cast<const float4*>(xrow0 + k);
        const float4* pa1 = reinterpret_cast<const float4*>(xrow1 + k);
        float4 a0l = pa0[0], a0h = pa0[1];
        float4 a1l = pa1[0], a1h = pa1[1];
        f16x8 a0 = {(f16)a0l.x, (f16)a0l.y, (f16)a0l.z, (f16)a0l.w,
                    (f16)a0h.x, (f16)a0h.y, (f16)a0h.z, (f16)a0h.w};
        f16x8 a1 = {(f16)a1l.x, (f16)a1l.y, (f16)a1l.z, (f16)a1l.w,
                    (f16)a1h.x, (f16)a1h.y, (f16)a1h.z, (f16)a1h.w};
        f16x8 b0 = *reinterpret_cast<const f16x8*>(wrow0 + k);
        f16x8 b1 = *reinterpret_cast<const f16x8*>(wrow1 + k);
        acc[0][0] = __builtin_amdgcn_mfma_f32_16x16x32_f16(a0, b0, acc[0][0], 0, 0, 0);
        acc[0][1] = __builtin_amdgcn_mfma_f32_16x16x32_f16(a0, b1, acc[0][1], 0, 0, 0);
        acc[1][0] = __builtin_amdgcn_mfma_f32_16x16x32_f16(a1, b0, acc[1][0], 0, 0, 0);
        acc[1][1] = __builtin_amdgcn_mfma_f32_16x16x32_f16(a1, b1, acc[1][1], 0, 0, 0);
    }

#pragma unroll
    for (int mi = 0; mi < 2; ++mi)
#pragma unroll
        for (int ni = 0; ni < 2; ++ni) {
            int col = colBase + ni * 16 + lr;
            float bv = bias[col];
#pragma unroll
            for (int j = 0; j < 4; ++j) {
                int row = rowBase + mi * 16 + kg * 4 + j;
                xw16[(size_t)row * HB + col] = (f16)(acc[mi][ni][j] + bv);
            }
        }
}

// ---------- phase 2: persistent recurrence, sc1-coherent h exchange ----------
// 128 WGs x 512 thr (8 waves). WG owns 16 cols; wave w owns K slice [w*256,(w+1)*256),
// Wh frags in registers. h stores/loads are relaxed agent atomics (sc1: L2-bypass,
// coherent at L3). Barrier: release fetch_add + RELAXED spin + one acquire at exit.
__global__ __launch_bounds__(512) void k_rnn_persist(const f16* __restrict__ Wh16T,
                                                     const f16* __restrict__ xw16,
                                                     f16* __restrict__ hA,
                                                     f16* __restrict__ hB,
                                                     float* __restrict__ dout,
                                                     u32* __restrict__ cnt) {
    __shared__ float red[64][132];  // row-stride 132 floats: conflict-free-ish reduce
    int tid = threadIdx.x;
    int lane = tid & 63, w = tid >> 6;
    int lr = lane & 15, kg = lane >> 4;
    int n0 = blockIdx.x * 16;

    // preload B fragments: Wh16T[n0+lr][w*256 + s*32 + kg*8 .. +8]
    f16x8 bfrag[8];
    {
        const f16* brow = Wh16T + (size_t)(n0 + lr) * HB + w * 256 + kg * 8;
#pragma unroll
        for (int s = 0; s < 8; ++s) bfrag[s] = *(const f16x8*)(brow + s * 32);
    }

    int r_o = tid >> 3;      // reduce output row 0..63
    int c_o = tid & 7;       // col pair 0..7
    int colbase = n0 + 2 * c_o;

    f16* hcur = hA;   // read at step t (ignored at t=0)
    f16* hnext = hB;  // written at step t

    for (int t = 0; t < TT; ++t) {
        // xw load early — independent of h, hides under loads/MFMA
        u32 xwv = *(const u32*)(xw16 + ((size_t)t * BB + r_o) * HB + colbase);

        f32x4 acc[4] = {};
        if (t > 0) {
            const f16* abase = hcur + w * 256 + kg * 8;
#pragma unroll
            for (int m = 0; m < 4; ++m) {
                const f16* ar = abase + (size_t)(m * 16 + lr) * HB;
#pragma unroll
                for (int s = 0; s < 8; ++s) {
                    union { u64 q[2]; f16x8 v; } a;
                    a.q[0] = __hip_atomic_load((u64*)(ar + s * 32), __ATOMIC_RELAXED,
                                               __HIP_MEMORY_SCOPE_AGENT);
                    a.q[1] = __hip_atomic_load((u64*)(ar + s * 32 + 4), __ATOMIC_RELAXED,
                                               __HIP_MEMORY_SCOPE_AGENT);
                    acc[m] = __builtin_amdgcn_mfma_f32_16x16x32_f16(a.v, bfrag[s], acc[m],
                                                                    0, 0, 0);
                }
            }
        }

        // partials -> LDS: red[row][w*16+col]; banks ~2-way max (free)
#pragma unroll
        for (int m = 0; m < 4; ++m) {
            int rbase = m * 16 + kg * 4;
#pragma unroll
            for (int j = 0; j < 4; ++j)
                red[rbase + j][w * 16 + lr] = acc[m][j];
        }
        __syncthreads();

        // cross-wave reduce: thread (r_o, c_o) sums 8 partial float2s
        float s0 = 0.f, s1 = 0.f;
#pragma unroll
        for (int ww = 0; ww < 8; ++ww) {
            float2 v = *(const float2*)&red[r_o][ww * 16 + 2 * c_o];
            s0 += v.x;
            s1 += v.y;
        }
        union { u32 u; f16 h[2]; } xwu;
        xwu.u = xwv;
        float p0 = s0 + (float)xwu.h[0];
        float p1 = s1 + (float)xwu.h[1];
        float h0v = tanhf(p0), h1v = tanhf(p1);

        if (t == TT - 1) {
            size_t o = (size_t)r_o * HB + colbase;
            dout[o] = h0v;
            dout[o + 1] = h1v;
        } else {
            union { u32 u; f16 h[2]; } ho;
            ho.h[0] = (f16)h0v;
            ho.h[1] = (f16)h1v;
            __hip_atomic_store((u32*)(hnext + (size_t)r_o * HB + colbase), ho.u,
                               __ATOMIC_RELAXED, __HIP_MEMORY_SCOPE_AGENT);
            __syncthreads();  // also separates LDS read (this step) from next step's writes
            if (tid == 0) {
                __hip_atomic_fetch_add(cnt, 1u, __ATOMIC_RELEASE, __HIP_MEMORY_SCOPE_AGENT);
                u32 tgt = (u32)NWG * (u32)(t + 1);
                while (__hip_atomic_load(cnt, __ATOMIC_RELAXED, __HIP_MEMORY_SCOPE_AGENT) < tgt)
                    __builtin_amdgcn_s_sleep(2);
                // one acquire to establish happens-before (single buffer_inv per step)
                (void)__hip_atomic_load(cnt, __ATOMIC_ACQUIRE, __HIP_MEMORY_SCOPE_AGENT);
            }
            __syncthreads();
        }
        f16* tmp = hcur;
        hcur = hnext;
        hnext = tmp;
    }
}

extern "C" void kernel_launch(void* const* d_in, const int* in_sizes, int n_in,
                              void* d_out, int out_size, void* d_ws, size_t ws_size,
                              hipStream_t stream) {
    const float* x = (const float*)d_in[0];
    const float* W = (const float*)d_in[1];
    const float* Wh = (const float*)d_in[2];
    const float* bias = (const float*)d_in[3];
    float* dout = (float*)d_out;

    char* ws = (char*)d_ws;
    const size_t SZ_WT = (size_t)HB * DD * 2;       // 8 MB
    const size_t SZ_H = (size_t)BB * HB * 2;        // 256 KB
    const size_t SZ_XW = (size_t)TT * BB * HB * 2;  // 64 MB
    const size_t OFF_W = 0;
    const size_t OFF_WH = OFF_W + SZ_WT;
    const size_t OFF_H0 = OFF_WH + SZ_WT;
    const size_t OFF_H1 = OFF_H0 + SZ_H;
    const size_t OFF_CNT = OFF_H1 + SZ_H;
    const size_t OFF_XW = OFF_CNT + 4096;
    const size_t OFF_X16 = OFF_XW + SZ_XW;
    const size_t NEED_FULL = OFF_X16 + (size_t)TT * BB * DD * 2;

    f16* W16T = (f16*)(ws + OFF_W);
    f16* Wh16T = (f16*)(ws + OFF_WH);
    f16* h0 = (f16*)(ws + OFF_H0);
    f16* h1 = (f16*)(ws + OFF_H1);
    u32* cnt = (u32*)(ws + OFF_CNT);
    f16* xw16 = (f16*)(ws + OFF_XW);
    f16* x16 = (f16*)(ws + OFF_X16);

    dim3 tgrid(32, 32);
    k_transpose_cvt<<<tgrid, 256, 0, stream>>>(W, W16T);
    k_transpose_cvt<<<tgrid, 256, 0, stream>>>(Wh, Wh16T);

    if (ws_size >= NEED_FULL) {
        k_cvt_x<<<TT * BB, 256, 0, stream>>>(x, x16);
        k_gemm_xw_lds<<<dim3(HB / 128, TT * BB / 128), 256, 0, stream>>>(x16, W16T, bias, xw16);
    } else {
        k_gemm_xw_direct<<<dim3(HB / 64, TT * BB / 64), 256, 0, stream>>>(x, W16T, bias, xw16);
    }

    hipMemsetAsync(cnt, 0, sizeof(u32), stream);
    k_rnn_persist<<<NWG, 512, 0, stream>>>(Wh16T, xw16, h0, h1, dout, cnt);
}

// Round 4
// 3159.186 us; speedup vs baseline: 1.5734x; 1.5734x over previous
//
#include <hip/hip_runtime.h>
#include <hip/hip_bf16.h>
#include <hip/hip_fp16.h>

typedef _Float16 f16;
typedef _Float16 f16x8 __attribute__((ext_vector_type(8)));
typedef float f32x4 __attribute__((ext_vector_type(4)));
typedef unsigned int u32;
typedef unsigned long long u64;

#define HB 2048
#define DD 2048
#define TT 256
#define BB 64
#define NWG 128

typedef const __attribute__((address_space(1))) u32 gu32;
typedef __attribute__((address_space(3))) u32 lu32;

__device__ __forceinline__ void gl_lds16(const void* g, void* l) {
    __builtin_amdgcn_global_load_lds((gu32*)g, (lu32*)l, 16, 0, 0);
}

// ---------- transpose + convert fp32 [R][C] -> fp16 [C][R] (square 2048) ----------
__global__ __launch_bounds__(256) void k_transpose_cvt(const float* __restrict__ src,
                                                       f16* __restrict__ dst) {
    __shared__ f16 tile[64][65];
    int bx = blockIdx.x * 64;
    int by = blockIdx.y * 64;
    int tx = threadIdx.x & 63;
    int ty = threadIdx.x >> 6;
#pragma unroll
    for (int r = ty; r < 64; r += 4)
        tile[r][tx] = (f16)src[(size_t)(by + r) * HB + bx + tx];
    __syncthreads();
#pragma unroll
    for (int r = ty; r < 64; r += 4)
        dst[(size_t)(bx + r) * HB + by + tx] = tile[tx][r];
}

// ---------- convert/gather x [b][t][d] fp32 -> a16 [t*64+b][d] fp16 ----------
__global__ __launch_bounds__(256) void k_cvt_x(const float* __restrict__ x,
                                               f16* __restrict__ a16) {
    int r = blockIdx.x;  // r = t*64+b
    int d = threadIdx.x * 8;
    const float* src = x + ((size_t)(r & 63) * TT + (r >> 6)) * DD + d;
    float4 v0 = *(const float4*)src;
    float4 v1 = *(const float4*)(src + 4);
    f16x8 o = {(f16)v0.x, (f16)v0.y, (f16)v0.z, (f16)v0.w,
               (f16)v1.x, (f16)v1.y, (f16)v1.z, (f16)v1.w};
    *(f16x8*)(a16 + (size_t)r * DD + d) = o;
}

// ---------- phase 1 (fast): 128x128x32 LDS-staged MFMA GEMM, xw16 = a16 @ W + b ----------
__global__ __launch_bounds__(256) void k_gemm_xw_lds(const f16* __restrict__ a16,
                                                     const f16* __restrict__ W16T,
                                                     const float* __restrict__ bias,
                                                     f16* __restrict__ xw16) {
    __shared__ f16 As[128 * 32];
    __shared__ f16 Bs[128 * 32];
    int tid = threadIdx.x;
    int lane = tid & 63, w = tid >> 6;
    int wr = w >> 1, wc = w & 1;
    int lr = lane & 15, kg = lane >> 4;
    int rowBase = blockIdx.y * 128;
    int colBase = blockIdx.x * 128;

    f32x4 acc[4][4] = {};

    int r0 = tid >> 2, c0 = ((tid & 3) ^ ((r0 >> 1) & 3)) * 8;
    int u1 = tid + 256;
    int r1 = u1 >> 2, c1 = ((u1 & 3) ^ ((r1 >> 1) & 3)) * 8;
    const f16* gA0 = a16 + (size_t)(rowBase + r0) * DD + c0;
    const f16* gA1 = a16 + (size_t)(rowBase + r1) * DD + c1;
    const f16* gB0 = W16T + (size_t)(colBase + r0) * DD + c0;
    const f16* gB1 = W16T + (size_t)(colBase + r1) * DD + c1;
    f16* lA0 = As + (size_t)(w * 64) * 8;
    f16* lA1 = As + (size_t)(256 + w * 64) * 8;
    f16* lB0 = Bs + (size_t)(w * 64) * 8;
    f16* lB1 = Bs + (size_t)(256 + w * 64) * 8;

    for (int kk = 0; kk < DD; kk += 32) {
        gl_lds16(gA0 + kk, lA0);
        gl_lds16(gA1 + kk, lA1);
        gl_lds16(gB0 + kk, lB0);
        gl_lds16(gB1 + kk, lB1);
        __syncthreads();

        f16x8 af[4], bf[4];
#pragma unroll
        for (int mi = 0; mi < 4; ++mi) {
            int row = wr * 64 + mi * 16 + lr;
            af[mi] = *(const f16x8*)(As + row * 32 + (kg ^ ((row >> 1) & 3)) * 8);
        }
#pragma unroll
        for (int ni = 0; ni < 4; ++ni) {
            int rowb = wc * 64 + ni * 16 + lr;
            bf[ni] = *(const f16x8*)(Bs + rowb * 32 + (kg ^ ((rowb >> 1) & 3)) * 8);
        }
#pragma unroll
        for (int mi = 0; mi < 4; ++mi)
#pragma unroll
            for (int ni = 0; ni < 4; ++ni)
                acc[mi][ni] = __builtin_amdgcn_mfma_f32_16x16x32_f16(af[mi], bf[ni],
                                                                     acc[mi][ni], 0, 0, 0);
        __syncthreads();
    }

#pragma unroll
    for (int mi = 0; mi < 4; ++mi)
#pragma unroll
        for (int ni = 0; ni < 4; ++ni) {
            int col = colBase + wc * 64 + ni * 16 + lr;
            float bv = bias[col];
#pragma unroll
            for (int j = 0; j < 4; ++j) {
                int row = rowBase + wr * 64 + mi * 16 + kg * 4 + j;
                xw16[(size_t)row * HB + col] = (f16)(acc[mi][ni][j] + bv);
            }
        }
}

// ---------- phase 1 (fallback, small ws): direct-load GEMM from fp32 x ----------
__global__ __launch_bounds__(256) void k_gemm_xw_direct(const float* __restrict__ x,
                                                        const f16* __restrict__ W16T,
                                                        const float* __restrict__ bias,
                                                        f16* __restrict__ xw16) {
    int lane = threadIdx.x & 63;
    int w = threadIdx.x >> 6;
    int wr = w >> 1, wc = w & 1;
    int rowBase = blockIdx.y * 64 + wr * 32;
    int colBase = blockIdx.x * 64 + wc * 32;
    int lr = lane & 15;
    int kg = lane >> 4;

    f32x4 acc[2][2] = {};

    int r0 = rowBase + lr;
    int r1 = rowBase + 16 + lr;
    const float* xrow0 = x + ((size_t)(r0 & 63) * TT + (r0 >> 6)) * DD;
    const float* xrow1 = x + ((size_t)(r1 & 63) * TT + (r1 >> 6)) * DD;
    const f16* wrow0 = W16T + (size_t)(colBase + lr) * DD;
    const f16* wrow1 = W16T + (size_t)(colBase + 16 + lr) * DD;

    for (int kk = 0; kk < DD; kk += 32) {
        int k = kk + kg * 8;
        const float4* pa0 = reinterpret_cast<const float4*>(xrow0 + k);
        const float4* pa1 = reinterpret_cast<const float4*>(xrow1 + k);
        float4 a0l = pa0[0], a0h = pa0[1];
        float4 a1l = pa1[0], a1h = pa1[1];
        f16x8 a0 = {(f16)a0l.x, (f16)a0l.y, (f16)a0l.z, (f16)a0l.w,
                    (f16)a0h.x, (f16)a0h.y, (f16)a0h.z, (f16)a0h.w};
        f16x8 a1 = {(f16)a1l.x, (f16)a1l.y, (f16)a1l.z, (f16)a1l.w,
                    (f16)a1h.x, (f16)a1h.y, (f16)a1h.z, (f16)a1h.w};
        f16x8 b0 = *reinterpret_cast<const f16x8*>(wrow0 + k);
        f16x8 b1 = *reinterpret_cast<const f16x8*>(wrow1 + k);
        acc[0][0] = __builtin_amdgcn_mfma_f32_16x16x32_f16(a0, b0, acc[0][0], 0, 0, 0);
        acc[0][1] = __builtin_amdgcn_mfma_f32_16x16x32_f16(a0, b1, acc[0][1], 0, 0, 0);
        acc[1][0] = __builtin_amdgcn_mfma_f32_16x16x32_f16(a1, b0, acc[1][0], 0, 0, 0);
        acc[1][1] = __builtin_amdgcn_mfma_f32_16x16x32_f16(a1, b1, acc[1][1], 0, 0, 0);
    }

#pragma unroll
    for (int mi = 0; mi < 2; ++mi)
#pragma unroll
        for (int ni = 0; ni < 2; ++ni) {
            int col = colBase + ni * 16 + lr;
            float bv = bias[col];
#pragma unroll
            for (int j = 0; j < 4; ++j) {
                int row = rowBase + mi * 16 + kg * 4 + j;
                xw16[(size_t)row * HB + col] = (f16)(acc[mi][ni][j] + bv);
            }
        }
}

// ---------- phase 2: persistent recurrence ----------
// 128 WGs x 512 thr (8 waves). WG owns 16 cols; wave w owns K slice [w*256,(w+1)*256),
// Wh frags in registers.
// h exchange: sc1 write-through stores (atomic relaxed agent) + PLAIN cacheable b128
// loads; coherence via one fence(acquire, agent) per WG per step after the barrier.
// Barrier: counter+broadcast — WGs add to cnt (no polling on it except WG0); WG0 polls
// cnt and publishes epoch; the rest poll epoch (read-only line => no L3 line contention).
__global__ __launch_bounds__(512) void k_rnn_persist(const f16* __restrict__ Wh16T,
                                                     const f16* __restrict__ xw16,
                                                     f16* __restrict__ hA,
                                                     f16* __restrict__ hB,
                                                     float* __restrict__ dout,
                                                     u32* __restrict__ bar) {
    __shared__ float red[64][132];  // row-stride 132 floats: ~2-way max bank aliasing
    u32* cnt = bar;
    u32* epoch = bar + 64;  // 256B away: separate cacheline
    int tid = threadIdx.x;
    int lane = tid & 63, w = tid >> 6;
    int lr = lane & 15, kg = lane >> 4;
    int n0 = blockIdx.x * 16;

    // preload B fragments: Wh16T[n0+lr][w*256 + s*32 + kg*8 .. +8] (registers, fence-immune)
    f16x8 bfrag[8];
    {
        const f16* brow = Wh16T + (size_t)(n0 + lr) * HB + w * 256 + kg * 8;
#pragma unroll
        for (int s = 0; s < 8; ++s) bfrag[s] = *(const f16x8*)(brow + s * 32);
    }

    int r_o = tid >> 3;  // reduce output row 0..63
    int c_o = tid & 7;   // col pair 0..7
    int colbase = n0 + 2 * c_o;

    f16* hcur = hA;
    f16* hnext = hB;

    for (int t = 0; t < TT; ++t) {
        // xw load early — independent of h, hides under h-loads/MFMA
        u32 xwv = *(const u32*)(xw16 + ((size_t)t * BB + r_o) * HB + colbase);

        f32x4 acc[4] = {};
        if (t > 0) {
            const f16* abase = hcur + w * 256 + kg * 8;
#pragma unroll
            for (int m = 0; m < 4; ++m) {
                const f16* ar = abase + (size_t)(m * 16 + lr) * HB;
#pragma unroll
                for (int s = 0; s < 8; ++s) {
                    f16x8 a = *(const f16x8*)(ar + s * 32);  // plain b128, L1/L2 cached
                    acc[m] = __builtin_amdgcn_mfma_f32_16x16x32_f16(a, bfrag[s], acc[m],
                                                                    0, 0, 0);
                }
            }
        }

        // partials -> LDS: red[row][w*16+col]
#pragma unroll
        for (int m = 0; m < 4; ++m) {
            int rbase = m * 16 + kg * 4;
#pragma unroll
            for (int j = 0; j < 4; ++j)
                red[rbase + j][w * 16 + lr] = acc[m][j];
        }
        __syncthreads();

        // cross-wave reduce: thread (r_o, c_o) sums 8 partial float2s
        float s0 = 0.f, s1 = 0.f;
#pragma unroll
        for (int ww = 0; ww < 8; ++ww) {
            float2 v = *(const float2*)&red[r_o][ww * 16 + 2 * c_o];
            s0 += v.x;
            s1 += v.y;
        }
        union { u32 u; f16 h[2]; } xwu;
        xwu.u = xwv;
        float p0 = s0 + (float)xwu.h[0];
        float p1 = s1 + (float)xwu.h[1];
        float h0v = tanhf(p0), h1v = tanhf(p1);

        if (t == TT - 1) {
            size_t o = (size_t)r_o * HB + colbase;
            dout[o] = h0v;
            dout[o + 1] = h1v;
        } else {
            union { u32 u; f16 h[2]; } ho;
            ho.h[0] = (f16)h0v;
            ho.h[1] = (f16)h1v;
            // write-through to L3 (sc1), keeps L2 clean
            __hip_atomic_store((u32*)(hnext + (size_t)r_o * HB + colbase), ho.u,
                               __ATOMIC_RELAXED, __HIP_MEMORY_SCOPE_AGENT);
            asm volatile("s_waitcnt vmcnt(0)" ::: "memory");  // h at L3 before signaling
            __syncthreads();  // all waves' stores drained; also protects LDS reuse
            if (tid == 0) {
                u32 tgt = (u32)(t + 1);
                __hip_atomic_fetch_add(cnt, 1u, __ATOMIC_RELAXED, __HIP_MEMORY_SCOPE_AGENT);
                if (blockIdx.x == 0) {
                    while (__hip_atomic_load(cnt, __ATOMIC_RELAXED,
                                             __HIP_MEMORY_SCOPE_AGENT) < (u32)NWG * tgt)
                        __builtin_amdgcn_s_sleep(1);
                    __hip_atomic_store(epoch, tgt, __ATOMIC_RELAXED,
                                       __HIP_MEMORY_SCOPE_AGENT);
                } else {
                    while (__hip_atomic_load(epoch, __ATOMIC_RELAXED,
                                             __HIP_MEMORY_SCOPE_AGENT) < tgt)
                        __builtin_amdgcn_s_sleep(1);
                }
                // invalidate L1/L2 once per step so plain h loads see remote writes
                __builtin_amdgcn_fence(__ATOMIC_ACQUIRE, "agent");
            }
            __syncthreads();
        }
        f16* tmp = hcur;
        hcur = hnext;
        hnext = tmp;
    }
}

extern "C" void kernel_launch(void* const* d_in, const int* in_sizes, int n_in,
                              void* d_out, int out_size, void* d_ws, size_t ws_size,
                              hipStream_t stream) {
    const float* x = (const float*)d_in[0];
    const float* W = (const float*)d_in[1];
    const float* Wh = (const float*)d_in[2];
    const float* bias = (const float*)d_in[3];
    float* dout = (float*)d_out;

    char* ws = (char*)d_ws;
    const size_t SZ_WT = (size_t)HB * DD * 2;       // 8 MB
    const size_t SZ_H = (size_t)BB * HB * 2;        // 256 KB
    const size_t SZ_XW = (size_t)TT * BB * HB * 2;  // 64 MB
    const size_t OFF_W = 0;
    const size_t OFF_WH = OFF_W + SZ_WT;
    const size_t OFF_H0 = OFF_WH + SZ_WT;
    const size_t OFF_H1 = OFF_H0 + SZ_H;
    const size_t OFF_CNT = OFF_H1 + SZ_H;
    const size_t OFF_XW = OFF_CNT + 4096;
    const size_t OFF_X16 = OFF_XW + SZ_XW;
    const size_t NEED_FULL = OFF_X16 + (size_t)TT * BB * DD * 2;

    f16* W16T = (f16*)(ws + OFF_W);
    f16* Wh16T = (f16*)(ws + OFF_WH);
    f16* h0 = (f16*)(ws + OFF_H0);
    f16* h1 = (f16*)(ws + OFF_H1);
    u32* bar = (u32*)(ws + OFF_CNT);
    f16* xw16 = (f16*)(ws + OFF_XW);
    f16* x16 = (f16*)(ws + OFF_X16);

    dim3 tgrid(32, 32);
    k_transpose_cvt<<<tgrid, 256, 0, stream>>>(W, W16T);
    k_transpose_cvt<<<tgrid, 256, 0, stream>>>(Wh, Wh16T);

    if (ws_size >= NEED_FULL) {
        k_cvt_x<<<TT * BB, 256, 0, stream>>>(x, x16);
        k_gemm_xw_lds<<<dim3(HB / 128, TT * BB / 128), 256, 0, stream>>>(x16, W16T, bias, xw16);
    } else {
        k_gemm_xw_direct<<<dim3(HB / 64, TT * BB / 64), 256, 0, stream>>>(x, W16T, bias, xw16);
    }

    hipMemsetAsync(bar, 0, 512, stream);
    k_rnn_persist<<<NWG, 512, 0, stream>>>(Wh16T, xw16, h0, h1, dout, bar);
}

// Round 5
// 3131.313 us; speedup vs baseline: 1.5874x; 1.0089x over previous
//
#include <hip/hip_runtime.h>
#include <hip/hip_bf16.h>
#include <hip/hip_fp16.h>

typedef _Float16 f16;
typedef _Float16 f16x8 __attribute__((ext_vector_type(8)));
typedef float f32x4 __attribute__((ext_vector_type(4)));
typedef unsigned int u32;
typedef unsigned long long u64;

#define HB 2048
#define DD 2048
#define TT 256
#define BB 64
#define CWG 64  // persistent WGs (32 cols each)

typedef const __attribute__((address_space(1))) u32 gu32;
typedef __attribute__((address_space(3))) u32 lu32;

__device__ __forceinline__ void gl_lds16(const void* g, void* l) {
    __builtin_amdgcn_global_load_lds((gu32*)g, (lu32*)l, 16, 0, 0);
}

// ---------- transpose + convert fp32 [R][C] -> fp16 [C][R] (square 2048) ----------
__global__ __launch_bounds__(256) void k_transpose_cvt(const float* __restrict__ src,
                                                       f16* __restrict__ dst) {
    __shared__ f16 tile[64][65];
    int bx = blockIdx.x * 64;
    int by = blockIdx.y * 64;
    int tx = threadIdx.x & 63;
    int ty = threadIdx.x >> 6;
#pragma unroll
    for (int r = ty; r < 64; r += 4)
        tile[r][tx] = (f16)src[(size_t)(by + r) * HB + bx + tx];
    __syncthreads();
#pragma unroll
    for (int r = ty; r < 64; r += 4)
        dst[(size_t)(bx + r) * HB + by + tx] = tile[tx][r];
}

// ---------- convert/gather x [b][t][d] fp32 -> a16 [t*64+b][d] fp16 ----------
__global__ __launch_bounds__(256) void k_cvt_x(const float* __restrict__ x,
                                               f16* __restrict__ a16) {
    int r = blockIdx.x;  // r = t*64+b
    int d = threadIdx.x * 8;
    const float* src = x + ((size_t)(r & 63) * TT + (r >> 6)) * DD + d;
    float4 v0 = *(const float4*)src;
    float4 v1 = *(const float4*)(src + 4);
    f16x8 o = {(f16)v0.x, (f16)v0.y, (f16)v0.z, (f16)v0.w,
               (f16)v1.x, (f16)v1.y, (f16)v1.z, (f16)v1.w};
    *(f16x8*)(a16 + (size_t)r * DD + d) = o;
}

// ---------- phase 1: 128x128x32 LDS-staged MFMA GEMM, xw16 = a16 @ W + b ----------
__global__ __launch_bounds__(256) void k_gemm_xw_lds(const f16* __restrict__ a16,
                                                     const f16* __restrict__ W16T,
                                                     const float* __restrict__ bias,
                                                     f16* __restrict__ xw16) {
    __shared__ f16 As[128 * 32];
    __shared__ f16 Bs[128 * 32];
    int tid = threadIdx.x;
    int lane = tid & 63, w = tid >> 6;
    int wr = w >> 1, wc = w & 1;
    int lr = lane & 15, kg = lane >> 4;
    int rowBase = blockIdx.y * 128;
    int colBase = blockIdx.x * 128;

    f32x4 acc[4][4] = {};

    int r0 = tid >> 2, c0 = ((tid & 3) ^ ((r0 >> 1) & 3)) * 8;
    int u1 = tid + 256;
    int r1 = u1 >> 2, c1 = ((u1 & 3) ^ ((r1 >> 1) & 3)) * 8;
    const f16* gA0 = a16 + (size_t)(rowBase + r0) * DD + c0;
    const f16* gA1 = a16 + (size_t)(rowBase + r1) * DD + c1;
    const f16* gB0 = W16T + (size_t)(colBase + r0) * DD + c0;
    const f16* gB1 = W16T + (size_t)(colBase + r1) * DD + c1;
    f16* lA0 = As + (size_t)(w * 64) * 8;
    f16* lA1 = As + (size_t)(256 + w * 64) * 8;
    f16* lB0 = Bs + (size_t)(w * 64) * 8;
    f16* lB1 = Bs + (size_t)(256 + w * 64) * 8;

    for (int kk = 0; kk < DD; kk += 32) {
        gl_lds16(gA0 + kk, lA0);
        gl_lds16(gA1 + kk, lA1);
        gl_lds16(gB0 + kk, lB0);
        gl_lds16(gB1 + kk, lB1);
        __syncthreads();

        f16x8 af[4], bf[4];
#pragma unroll
        for (int mi = 0; mi < 4; ++mi) {
            int row = wr * 64 + mi * 16 + lr;
            af[mi] = *(const f16x8*)(As + row * 32 + (kg ^ ((row >> 1) & 3)) * 8);
        }
#pragma unroll
        for (int ni = 0; ni < 4; ++ni) {
            int rowb = wc * 64 + ni * 16 + lr;
            bf[ni] = *(const f16x8*)(Bs + rowb * 32 + (kg ^ ((rowb >> 1) & 3)) * 8);
        }
#pragma unroll
        for (int mi = 0; mi < 4; ++mi)
#pragma unroll
            for (int ni = 0; ni < 4; ++ni)
                acc[mi][ni] = __builtin_amdgcn_mfma_f32_16x16x32_f16(af[mi], bf[ni],
                                                                     acc[mi][ni], 0, 0, 0);
        __syncthreads();
    }

#pragma unroll
    for (int mi = 0; mi < 4; ++mi)
#pragma unroll
        for (int ni = 0; ni < 4; ++ni) {
            int col = colBase + wc * 64 + ni * 16 + lr;
            float bv = bias[col];
#pragma unroll
            for (int j = 0; j < 4; ++j) {
                int row = rowBase + wr * 64 + mi * 16 + kg * 4 + j;
                xw16[(size_t)row * HB + col] = (f16)(acc[mi][ni][j] + bv);
            }
        }
}

// ---------- phase 1 (fallback, small ws) ----------
__global__ __launch_bounds__(256) void k_gemm_xw_direct(const float* __restrict__ x,
                                                        const f16* __restrict__ W16T,
                                                        const float* __restrict__ bias,
                                                        f16* __restrict__ xw16) {
    int lane = threadIdx.x & 63;
    int w = threadIdx.x >> 6;
    int wr = w >> 1, wc = w & 1;
    int rowBase = blockIdx.y * 64 + wr * 32;
    int colBase = blockIdx.x * 64 + wc * 32;
    int lr = lane & 15;
    int kg = lane >> 4;

    f32x4 acc[2][2] = {};

    int r0 = rowBase + lr;
    int r1 = rowBase + 16 + lr;
    const float* xrow0 = x + ((size_t)(r0 & 63) * TT + (r0 >> 6)) * DD;
    const float* xrow1 = x + ((size_t)(r1 & 63) * TT + (r1 >> 6)) * DD;
    const f16* wrow0 = W16T + (size_t)(colBase + lr) * DD;
    const f16* wrow1 = W16T + (size_t)(colBase + 16 + lr) * DD;

    for (int kk = 0; kk < DD; kk += 32) {
        int k = kk + kg * 8;
        const float4* pa0 = reinterpret_cast<const float4*>(xrow0 + k);
        const float4* pa1 = reinterpret_cast<const float4*>(xrow1 + k);
        float4 a0l = pa0[0], a0h = pa0[1];
        float4 a1l = pa1[0], a1h = pa1[1];
        f16x8 a0 = {(f16)a0l.x, (f16)a0l.y, (f16)a0l.z, (f16)a0l.w,
                    (f16)a0h.x, (f16)a0h.y, (f16)a0h.z, (f16)a0h.w};
        f16x8 a1 = {(f16)a1l.x, (f16)a1l.y, (f16)a1l.z, (f16)a1l.w,
                    (f16)a1h.x, (f16)a1h.y, (f16)a1h.z, (f16)a1h.w};
        f16x8 b0 = *reinterpret_cast<const f16x8*>(wrow0 + k);
        f16x8 b1 = *reinterpret_cast<const f16x8*>(wrow1 + k);
        acc[0][0] = __builtin_amdgcn_mfma_f32_16x16x32_f16(a0, b0, acc[0][0], 0, 0, 0);
        acc[0][1] = __builtin_amdgcn_mfma_f32_16x16x32_f16(a0, b1, acc[0][1], 0, 0, 0);
        acc[1][0] = __builtin_amdgcn_mfma_f32_16x16x32_f16(a1, b0, acc[1][0], 0, 0, 0);
        acc[1][1] = __builtin_amdgcn_mfma_f32_16x16x32_f16(a1, b1, acc[1][1], 0, 0, 0);
    }

#pragma unroll
    for (int mi = 0; mi < 2; ++mi)
#pragma unroll
        for (int ni = 0; ni < 2; ++ni) {
            int col = colBase + ni * 16 + lr;
            float bv = bias[col];
#pragma unroll
            for (int j = 0; j < 4; ++j) {
                int row = rowBase + mi * 16 + kg * 4 + j;
                xw16[(size_t)row * HB + col] = (f16)(acc[mi][ni][j] + bv);
            }
        }
}

// ---------- phase 2: persistent recurrence, 64 WGs x 512 thr ----------
// WG owns 32 cols; wave w owns K slice [w*256,(w+1)*256); Wh frags in registers
// (bfrag[2][8]). h: sc1 write-through stores + plain cached b128 loads + one
// acquire fence per WG/step. Barrier: NO atomics — per-WG monotone flag at 64B
// stride (store-only), every WG self-polls all 64 flags with wave0's 64 lanes.
__global__ __launch_bounds__(512, 2) void k_rnn_persist(const f16* __restrict__ Wh16T,
                                                        const f16* __restrict__ xw16,
                                                        f16* __restrict__ hA,
                                                        f16* __restrict__ hB,
                                                        float* __restrict__ dout,
                                                        u32* __restrict__ bar) {
    __shared__ float red[64][260];  // 65 KB
    int tid = threadIdx.x;
    int lane = tid & 63, w = tid >> 6;
    int lr = lane & 15, kg = lane >> 4;
    int n0 = blockIdx.x * 32;

    // preload B fragments: Wh16T[n0+ni*16+lr][w*256 + s*32 + kg*8 .. +8]
    f16x8 bfrag[2][8];
#pragma unroll
    for (int ni = 0; ni < 2; ++ni) {
        const f16* brow = Wh16T + (size_t)(n0 + ni * 16 + lr) * HB + w * 256 + kg * 8;
#pragma unroll
        for (int s = 0; s < 8; ++s) bfrag[ni][s] = *(const f16x8*)(brow + s * 32);
    }

    int r_o = tid >> 3;        // 0..63
    int c4 = (tid & 7) * 4;    // 0,4,...,28
    int colbase = n0 + c4;

    f16* hcur = hA;
    f16* hnext = hB;

    for (int t = 0; t < TT; ++t) {
        // xw load early (independent of h)
        u64 xwv = *(const u64*)(xw16 + ((size_t)t * BB + r_o) * HB + colbase);

        f32x4 acc[4][2] = {};
        if (t > 0) {
            const f16* abase = hcur + w * 256 + kg * 8;
#pragma unroll
            for (int m = 0; m < 4; ++m) {
                const f16* ar = abase + (size_t)(m * 16 + lr) * HB;
#pragma unroll
                for (int s = 0; s < 8; ++s) {
                    f16x8 a = *(const f16x8*)(ar + s * 32);  // plain b128, cached
                    acc[m][0] = __builtin_amdgcn_mfma_f32_16x16x32_f16(a, bfrag[0][s],
                                                                       acc[m][0], 0, 0, 0);
                    acc[m][1] = __builtin_amdgcn_mfma_f32_16x16x32_f16(a, bfrag[1][s],
                                                                       acc[m][1], 0, 0, 0);
                }
            }
        }

        // partials -> LDS: red[row][w*32 + ni*16 + lr]
#pragma unroll
        for (int m = 0; m < 4; ++m)
#pragma unroll
            for (int ni = 0; ni < 2; ++ni) {
                int rbase = m * 16 + kg * 4;
#pragma unroll
                for (int j = 0; j < 4; ++j)
                    red[rbase + j][w * 32 + ni * 16 + lr] = acc[m][ni][j];
            }
        __syncthreads();

        // cross-wave reduce: thread (r_o, c4) sums 8 float4 partials
        float4 sum = {0.f, 0.f, 0.f, 0.f};
#pragma unroll
        for (int ww = 0; ww < 8; ++ww) {
            float4 v = *(const float4*)&red[r_o][ww * 32 + c4];
            sum.x += v.x; sum.y += v.y; sum.z += v.z; sum.w += v.w;
        }
        union { u64 q; f16 h[4]; } xwu;
        xwu.q = xwv;
        float h0v = tanhf(sum.x + (float)xwu.h[0]);
        float h1v = tanhf(sum.y + (float)xwu.h[1]);
        float h2v = tanhf(sum.z + (float)xwu.h[2]);
        float h3v = tanhf(sum.w + (float)xwu.h[3]);

        if (t == TT - 1) {
            float4 o = {h0v, h1v, h2v, h3v};
            *(float4*)(dout + (size_t)r_o * HB + colbase) = o;
        } else {
            union { u64 q; f16 h[4]; } ho;
            ho.h[0] = (f16)h0v; ho.h[1] = (f16)h1v;
            ho.h[2] = (f16)h2v; ho.h[3] = (f16)h3v;
            // write-through to L3 (sc1)
            __hip_atomic_store((u64*)(hnext + (size_t)r_o * HB + colbase), ho.q,
                               __ATOMIC_RELAXED, __HIP_MEMORY_SCOPE_AGENT);
            asm volatile("s_waitcnt vmcnt(0)" ::: "memory");  // h at L3 before flag
            __syncthreads();  // all waves drained; also protects LDS reuse
            if (tid < 64) {
                u32 tgt = (u32)(t + 1);
                if (tid == 0)
                    __hip_atomic_store(bar + (size_t)blockIdx.x * 16, tgt,
                                       __ATOMIC_RELAXED, __HIP_MEMORY_SCOPE_AGENT);
                u32 v = __hip_atomic_load(bar + (size_t)lane * 16, __ATOMIC_RELAXED,
                                          __HIP_MEMORY_SCOPE_AGENT);
                while (!__all(v >= tgt)) {
                    __builtin_amdgcn_s_sleep(1);
                    v = __hip_atomic_load(bar + (size_t)lane * 16, __ATOMIC_RELAXED,
                                          __HIP_MEMORY_SCOPE_AGENT);
                }
                // invalidate L1/L2 once so plain h loads see remote writes
                __builtin_amdgcn_fence(__ATOMIC_ACQUIRE, "agent");
            }
            __syncthreads();
        }
        f16* tmp = hcur;
        hcur = hnext;
        hnext = tmp;
    }
}

extern "C" void kernel_launch(void* const* d_in, const int* in_sizes, int n_in,
                              void* d_out, int out_size, void* d_ws, size_t ws_size,
                              hipStream_t stream) {
    const float* x = (const float*)d_in[0];
    const float* W = (const float*)d_in[1];
    const float* Wh = (const float*)d_in[2];
    const float* bias = (const float*)d_in[3];
    float* dout = (float*)d_out;

    char* ws = (char*)d_ws;
    const size_t SZ_WT = (size_t)HB * DD * 2;       // 8 MB
    const size_t SZ_H = (size_t)BB * HB * 2;        // 256 KB
    const size_t SZ_XW = (size_t)TT * BB * HB * 2;  // 64 MB
    const size_t OFF_W = 0;
    const size_t OFF_WH = OFF_W + SZ_WT;
    const size_t OFF_H0 = OFF_WH + SZ_WT;
    const size_t OFF_H1 = OFF_H0 + SZ_H;
    const size_t OFF_CNT = OFF_H1 + SZ_H;
    const size_t OFF_XW = OFF_CNT + 4096;
    const size_t OFF_X16 = OFF_XW + SZ_XW;
    const size_t NEED_FULL = OFF_X16 + (size_t)TT * BB * DD * 2;

    f16* W16T = (f16*)(ws + OFF_W);
    f16* Wh16T = (f16*)(ws + OFF_WH);
    f16* h0 = (f16*)(ws + OFF_H0);
    f16* h1 = (f16*)(ws + OFF_H1);
    u32* bar = (u32*)(ws + OFF_CNT);
    f16* xw16 = (f16*)(ws + OFF_XW);
    f16* x16 = (f16*)(ws + OFF_X16);

    dim3 tgrid(32, 32);
    k_transpose_cvt<<<tgrid, 256, 0, stream>>>(W, W16T);
    k_transpose_cvt<<<tgrid, 256, 0, stream>>>(Wh, Wh16T);

    if (ws_size >= NEED_FULL) {
        k_cvt_x<<<TT * BB, 256, 0, stream>>>(x, x16);
        k_gemm_xw_lds<<<dim3(HB / 128, TT * BB / 128), 256, 0, stream>>>(x16, W16T, bias, xw16);
    } else {
        k_gemm_xw_direct<<<dim3(HB / 64, TT * BB / 64), 256, 0, stream>>>(x, W16T, bias, xw16);
    }

    hipMemsetAsync(bar, 0, 4096, stream);
    k_rnn_persist<<<CWG, 512, 0, stream>>>(Wh16T, xw16, h0, h1, dout, bar);
}